// Round 1
// baseline (487.631 us; speedup 1.0000x reference)
//
#include <hip/hip_runtime.h>
#include <hip/hip_bf16.h>
#include <math.h>

#define S_LEN 4096
#define DHEAD 128
#define NHEAD 8
#define LASTQ 64
#define V_TOPK 1024
#define S_TOPK 2048
#define FORCE_V 30
#define FORCE_S 100

#define SCALE 0.08838834764831845f
#define NEGBIG -3.0e38f

#define NJOBS 111   // split-K jobs per head (chunks of <=11 k-tiles)

typedef __attribute__((ext_vector_type(8))) short short8;
typedef __attribute__((ext_vector_type(4))) float floatx4;
typedef unsigned long long u64;

__device__ __forceinline__ unsigned short f2bf(float f) {
    unsigned u = __float_as_uint(f);
    unsigned r = (u + 0x7fffu + ((u >> 16) & 1u)) >> 16;   // RNE
    return (unsigned short)r;
}
__device__ __forceinline__ float bf2f(unsigned short s) {
    unsigned u = ((unsigned)s) << 16;
    return __uint_as_float(u);
}

// ---- split-K job tables: per head, q-block Q in [0,32) (128 rows each),
// k-range [K0,K1) in 64-key tiles; job id == partial index. ----
__device__ const short jobQ[NJOBS] = {
    0,1,2,3,4, 5,5, 6,6, 7,7, 8,8, 9,9, 10,10,
    11,11,11, 12,12,12, 13,13,13, 14,14,14, 15,15,15,
    16,16,16,16, 17,17,17,17, 18,18,18,18, 19,19,19,19, 20,20,20,20, 21,21,21,21,
    22,22,22,22,22, 23,23,23,23,23, 24,24,24,24,24, 25,25,25,25,25, 26,26,26,26,26,
    27,27,27,27,27,27, 28,28,28,28,28,28, 29,29,29,29,29,29, 30,30,30,30,30,30,
    31,31,31,31,31,31};
__device__ const short jobK0[NJOBS] = {
    0,0,0,0,0, 0,6, 0,7, 0,8, 0,9, 0,10, 0,11,
    0,8,16, 0,9,18, 0,10,19, 0,10,20, 0,11,22,
    0,9,18,26, 0,9,18,27, 0,10,20,29, 0,10,20,30, 0,11,22,32, 0,11,22,33,
    0,10,19,28,37, 0,10,20,30,39, 0,10,20,30,40, 0,11,22,32,42, 0,11,22,33,44,
    0,10,20,29,38,47, 0,10,20,30,40,49, 0,10,20,30,40,50, 0,11,22,32,42,52,
    0,11,22,33,44,54};
__device__ const short jobK1[NJOBS] = {
    2,4,6,8,10, 6,12, 7,14, 8,16, 9,18, 10,20, 11,22,
    8,16,24, 9,18,26, 10,19,28, 10,20,30, 11,22,32,
    9,18,26,34, 9,18,27,36, 10,20,29,38, 10,20,30,40, 11,22,32,42, 11,22,33,44,
    10,19,28,37,46, 10,20,30,39,48, 10,20,30,40,50, 11,22,32,42,52, 11,22,33,44,54,
    10,20,29,38,47,56, 10,20,30,40,49,58, 10,20,30,40,50,60, 11,22,32,42,52,62,
    11,22,33,44,54,64};
__device__ const short pBase[32] = {0,1,2,3,4,5,7,9,11,13,15,17,20,23,26,29,
                                    32,36,40,44,48,52,56,61,66,71,76,81,87,93,99,105};
__device__ const short pCnt[32]  = {1,1,1,1,1,2,2,2,2,2,2,3,3,3,3,3,
                                    4,4,4,4,4,4,5,5,5,5,5,6,6,6,6,6};

// ---------------------------------------------------------------------------
// Fused prep + score_qk (independent work, one launch):
//   blocks 0..511    : K fp32->bf16
//   blocks 512..1535 : V transpose -> Vt[h][d][s] bf16
//   blocks 1536..2047: scores[h][qi][j] for last-64 queries (fp32 topk-faithful)
// ---------------------------------------------------------------------------
__global__ __launch_bounds__(256) void prep_score(const float* __restrict__ q,
                                                  const float* __restrict__ k,
                                                  const float* __restrict__ v,
                                                  unsigned short* __restrict__ kbf,
                                                  unsigned short* __restrict__ vtbf,
                                                  float* __restrict__ scores) {
    int b = blockIdx.x, t = threadIdx.x;
    __shared__ __align__(16) float4 SH[64 * 32];   // 32 KB, aliased per branch

    if (b < 512) {
        const float4* src = (const float4*)k;
        int base = b * 2048;
#pragma unroll
        for (int i = 0; i < 8; ++i) {
            int idx = base + i * 256 + t;
            float4 val = src[idx];
            ushort4 o;
            o.x = f2bf(val.x); o.y = f2bf(val.y); o.z = f2bf(val.z); o.w = f2bf(val.w);
            ((ushort4*)kbf)[idx] = o;
        }
    } else if (b < 1536) {
        int bx = b - 512;
        int h  = bx >> 7;
        int rem = bx & 127;
        int d0 = (rem >> 6) * 64;
        int k0 = (rem & 63) * 64;
        unsigned short (*T)[72] = reinterpret_cast<unsigned short(*)[72]>(SH);
#pragma unroll
        for (int it = 0; it < 4; ++it) {
            int idx = t + it * 256;
            int r = idx >> 4, c4 = idx & 15;
            float4 val = *(const float4*)(v + ((size_t)(h * S_LEN) + k0 + r) * DHEAD + d0 + c4 * 4);
            T[c4 * 4 + 0][r] = f2bf(val.x);
            T[c4 * 4 + 1][r] = f2bf(val.y);
            T[c4 * 4 + 2][r] = f2bf(val.z);
            T[c4 * 4 + 3][r] = f2bf(val.w);
        }
        __syncthreads();
#pragma unroll
        for (int it = 0; it < 2; ++it) {
            int idx = t + it * 256;
            int r = idx >> 3, c8 = idx & 7;
            *(uint4*)(vtbf + ((size_t)h * DHEAD + d0 + r) * S_LEN + k0 + c8 * 8) = *(uint4*)&T[r][c8 * 8];
        }
    } else {
        int bx = b - 1536;
        int h  = bx >> 6;
        int kt = bx & 63;
        int jl = t >> 2, part = t & 3;
        int j  = kt * 64 + jl;

        float4* Qs = (float4*)SH;
        const float4* qbase = (const float4*)(q + ((size_t)h * S_LEN + (S_LEN - LASTQ)) * DHEAD);
        for (int idx = t; idx < 64 * 32; idx += 256) Qs[idx] = qbase[idx];
        __syncthreads();

        float4 kr[8];
        const float4* kp = (const float4*)(k + ((size_t)h * S_LEN + j) * DHEAD) + part * 8;
#pragma unroll
        for (int c = 0; c < 8; ++c) kr[c] = kp[c];

        float* sp = scores + (size_t)h * LASTQ * S_LEN + j;
#pragma unroll 4
        for (int qi = 0; qi < LASTQ; ++qi) {
            const float4* qp4 = Qs + qi * 32 + part * 8;
            float dot = 0.f;
#pragma unroll
            for (int c = 0; c < 8; ++c) {
                float4 a = qp4[c], bb = kr[c];
                dot += a.x * bb.x + a.y * bb.y + a.z * bb.z + a.w * bb.w;
            }
            dot += __shfl_xor(dot, 1, 64);
            dot += __shfl_xor(dot, 2, 64);
            if (part == 0) {
                int qpos = S_LEN - LASTQ + qi;
                sp[(size_t)qi * S_LEN] = (j <= qpos) ? dot * SCALE : NEGBIG;
            }
        }
    }
}

// ---------------------------------------------------------------------------
// P2a: per-row softmax stats (m, 1/sum). 512 rows, one wave per row.
// ---------------------------------------------------------------------------
__global__ __launch_bounds__(256) void row_stats(const float* __restrict__ scores,
                                                 float* __restrict__ m_out,
                                                 float* __restrict__ inv_out) {
    int row  = blockIdx.x * 4 + (threadIdx.x >> 6);
    int lane = threadIdx.x & 63;
    const float4* rp = (const float4*)(scores + (size_t)row * S_LEN);
    float mx = NEGBIG;
    for (int i = lane; i < S_LEN / 4; i += 64) {
        float4 s4 = rp[i];
        mx = fmaxf(mx, fmaxf(fmaxf(s4.x, s4.y), fmaxf(s4.z, s4.w)));
    }
#pragma unroll
    for (int d = 32; d >= 1; d >>= 1) mx = fmaxf(mx, __shfl_xor(mx, d, 64));
    float su = 0.f;
    for (int i = lane; i < S_LEN / 4; i += 64) {
        float4 s4 = rp[i];
        su += __expf(s4.x - mx) + __expf(s4.y - mx) + __expf(s4.z - mx) + __expf(s4.w - mx);
    }
#pragma unroll
    for (int d = 32; d >= 1; d >>= 1) su += __shfl_xor(su, d, 64);
    if (lane == 0) { m_out[row] = mx; inv_out[row] = 1.0f / su; }
}

// ---------------------------------------------------------------------------
// P2b+B fused: per (head, {vertical,slash}) accumulate scores + exact
// k-th-largest radix select -> membership bitmask. 16 blocks x 1024 threads.
// ---------------------------------------------------------------------------
__global__ __launch_bounds__(1024) void pattern_finish(const float* __restrict__ scores,
                                                       const float* __restrict__ m_all,
                                                       const float* __restrict__ inv_all,
                                                       unsigned* __restrict__ col_mask,
                                                       unsigned* __restrict__ diag_mask) {
    int h   = blockIdx.x >> 1;
    int sel = blockIdx.x & 1;
    int t = threadIdx.x;
    int kwant  = sel ? S_TOPK : V_TOPK;
    int forced = sel ? FORCE_S : FORCE_V;
    unsigned* dst = sel ? (diag_mask + h * 128) : (col_mask + h * 128);

    __shared__ float sm[LASTQ], sv[LASTQ];
    __shared__ unsigned keys[S_LEN];
    __shared__ int hist[256];
    __shared__ int sh_digit, sh_want;

    if (t < LASTQ) { sm[t] = m_all[h * LASTQ + t]; sv[t] = inv_all[h * LASTQ + t]; }
    __syncthreads();

    const float* S0 = scores + (size_t)h * LASTQ * S_LEN;
#pragma unroll
    for (int rep = 0; rep < 4; ++rep) {
        int j = rep * 1024 + t;
        float acc = 0.f;
        if (sel == 0) {
            for (int r = 0; r < LASTQ; ++r)
                acc += __expf(S0[(size_t)r * S_LEN + j] - sm[r]) * sv[r];
        } else {
            for (int r = 0; r < LASTQ; ++r) {
                int idx = (S_LEN - LASTQ) + r - j;
                if (idx >= 0)
                    acc += __expf(S0[(size_t)r * S_LEN + idx] - sm[r]) * sv[r];
            }
        }
        float f = (j < forced) ? __builtin_inff() : acc;
        unsigned u = __float_as_uint(f);
        u = (u & 0x80000000u) ? ~u : (u | 0x80000000u);
        keys[j] = u;
    }
    __syncthreads();

    unsigned prefix = 0;
    int want = kwant;
    for (int shift = 24; shift >= 0; shift -= 8) {
        if (t < 256) hist[t] = 0;
        __syncthreads();
        for (int j = t; j < S_LEN; j += 1024) {
            unsigned key = keys[j];
            bool match = (shift == 24) || (((key ^ prefix) >> (shift + 8)) == 0);
            if (match) atomicAdd(&hist[(key >> shift) & 255u], 1);
        }
        __syncthreads();
        if (t == 0) {
            int cum = 0, d = 255;
            for (; d >= 0; --d) {
                cum += hist[d];
                if (cum >= want) break;
            }
            sh_digit = d;
            sh_want  = want - (cum - hist[d]);
        }
        __syncthreads();
        prefix |= ((unsigned)sh_digit) << shift;
        want = sh_want;
        __syncthreads();
    }
    if (t < 128) {
        unsigned bits = 0;
        for (int b = 0; b < 32; ++b)
            if (keys[t * 32 + b] >= prefix) bits |= (1u << b);
        dst[t] = bits;
    }
}

// ---------------------------------------------------------------------------
// Phase C: MFMA flash attention, 128 q-rows per block, split-K jobs.
// This round: reg-prefetch async staging (T14), XOR-swizzled unpadded Ks/Vt
// (LDS 55.1->51.5 KB => 3 blocks/CU), s_setprio around MFMA clusters,
// exact defer-rescale (skip alpha path when no row max grew).
// ---------------------------------------------------------------------------
#define PS_STRIDE 72

__global__ __launch_bounds__(256, 3) void sparse_attn_mfma(
        const float* __restrict__ q,
        const unsigned short* __restrict__ kbf,
        const unsigned short* __restrict__ vtbf,
        const unsigned* __restrict__ col_mask,
        const unsigned* __restrict__ diag_mask,
        unsigned short* __restrict__ pO, float* __restrict__ pm, float* __restrict__ pl) {
    int b = blockIdx.x;
    int h = b & 7;
    int job = b >> 3;                 // 0..110
    int Q  = jobQ[job];
    int k0 = jobK0[job];
    int k1 = jobK1[job];
    int i0 = Q * 128;
    int t    = threadIdx.x;
    int wave = t >> 6;
    int lane = t & 63;
    int ln16 = lane & 15;
    int quad = lane >> 4;
    int lsw  = ln16 & 7;              // row&7 for all LDS rows this lane touches

    // Unpadded tiles + XOR slot swizzle (16B slots, slot' = slot ^ (row&7)).
    // Read/write bank math: every access pattern lands 8 lanes per 4-bank
    // group == conflict-free minimum.
    __shared__ __align__(16) unsigned short Ks[64 * 128];
    __shared__ __align__(16) unsigned short Vt[128 * 64];
    __shared__ __align__(16) unsigned short Ps[8 * 16 * PS_STRIDE];
    __shared__ u64 allowed[128];
    __shared__ unsigned dmLDS[130];

    if (t < 130) dmLDS[t] = (t < 128) ? diag_mask[h * 128 + t] : 0u;

    // Q fragments for both 16-row subtiles (SCALE folded in), fp32 -> bf16
    short8 qf[2][4];
#pragma unroll
    for (int s = 0; s < 2; ++s) {
        int qrow = i0 + wave * 32 + s * 16 + ln16;
        const float* qp = q + ((size_t)h * S_LEN + qrow) * DHEAD;
#pragma unroll
        for (int ds = 0; ds < 4; ++ds) {
            int base = ds * 32 + quad * 8;
            float4 a = *(const float4*)(qp + base);
            float4 c = *(const float4*)(qp + base + 4);
            union { unsigned short u[8]; short8 v; } tmp;
            tmp.u[0] = f2bf(a.x * SCALE); tmp.u[1] = f2bf(a.y * SCALE);
            tmp.u[2] = f2bf(a.z * SCALE); tmp.u[3] = f2bf(a.w * SCALE);
            tmp.u[4] = f2bf(c.x * SCALE); tmp.u[5] = f2bf(c.y * SCALE);
            tmp.u[6] = f2bf(c.z * SCALE); tmp.u[7] = f2bf(c.w * SCALE);
            qf[s][ds] = tmp.v;
        }
    }

    floatx4 o4[2][8];
#pragma unroll
    for (int s = 0; s < 2; ++s)
#pragma unroll
        for (int n = 0; n < 8; ++n) o4[s][n] = (floatx4){0.f, 0.f, 0.f, 0.f};
    float m_run[2][4] = {{NEGBIG, NEGBIG, NEGBIG, NEGBIG}, {NEGBIG, NEGBIG, NEGBIG, NEGBIG}};
    float l_run[2][4] = {{0.f, 0.f, 0.f, 0.f}, {0.f, 0.f, 0.f, 0.f}};

    unsigned short* psw[2];
    psw[0] = Ps + (wave * 2 + 0) * 16 * PS_STRIDE;
    psw[1] = Ps + (wave * 2 + 1) * 16 * PS_STRIDE;

    const unsigned short* kgbase = kbf + (size_t)h * S_LEN * DHEAD;
    const unsigned short* vgbase = vtbf + (size_t)h * DHEAD * S_LEN;

    // T14 async-stage: prefetch next tile into regs while computing current.
    uint4 kreg[4], vreg[4];
    auto load_tile = [&](int j0_) {
#pragma unroll
        for (int it = 0; it < 4; ++it) {
            int idx = t + it * 256;
            kreg[it] = *(const uint4*)(kgbase + ((size_t)(j0_ + (idx >> 4))) * DHEAD + (idx & 15) * 8);
        }
#pragma unroll
        for (int it = 0; it < 4; ++it) {
            int idx = t + it * 256;
            vreg[it] = *(const uint4*)(vgbase + ((size_t)(idx >> 3)) * S_LEN + j0_ + (idx & 7) * 8);
        }
    };

    load_tile(k0 * 64);

    for (int jt = k0; jt < k1; ++jt) {
        int j0 = jt * 64;
        __syncthreads();   // previous iteration's LDS reads done

        // ---- write prefetched tile to LDS (swizzled) ----
#pragma unroll
        for (int it = 0; it < 4; ++it) {
            int idx = t + it * 256;
            int r = idx >> 4, c8 = idx & 15;
            *(uint4*)&Ks[r * 128 + ((c8 ^ (r & 7)) << 3)] = kreg[it];
        }
#pragma unroll
        for (int it = 0; it < 4; ++it) {
            int idx = t + it * 256;
            int r = idx >> 3, c8 = idx & 7;
            *(uint4*)&Vt[r * 64 + ((c8 ^ (r & 7)) << 3)] = vreg[it];
        }
        // ---- issue next tile's loads (latency hides under compute) ----
        if (jt + 1 < k1) load_tile(j0 + 64);

        // ---- per-row allowed bitmask (128 rows) ----
        if (t < 128) {
            int i = i0 + t;
            int off0 = i - j0;
            u64 a = 0;
            if (off0 >= 0) {
                u64 causal = (off0 >= 63) ? ~0ull : ((1ull << (off0 + 1)) - 1ull);
                u64 cwv = ((u64)col_mask[h * 128 + (j0 >> 5) + 1] << 32) |
                          (u64)col_mask[h * 128 + (j0 >> 5)];
                int sb = off0 - 63;
                u64 V;
                if (sb >= 0) {
                    int w = sb >> 5, sh = sb & 31;
                    u64 lo = ((u64)dmLDS[w + 1] << 32) | (u64)dmLDS[w];
                    u64 hi = (u64)dmLDS[w + 2];
                    V = (lo >> sh) | (sh ? (hi << (64 - sh)) : 0ull);
                } else {
                    u64 w0 = ((u64)dmLDS[1] << 32) | (u64)dmLDS[0];
                    V = w0 << (-sb);
                }
                a = (cwv | __brevll(V)) & causal;
            }
            allowed[t] = a;
        }
        __syncthreads();

        // ---- S = Q K^T, both subtiles share each K fragment ----
        floatx4 sa[2][4];
#pragma unroll
        for (int s = 0; s < 2; ++s)
#pragma unroll
            for (int c = 0; c < 4; ++c) sa[s][c] = (floatx4){0.f, 0.f, 0.f, 0.f};
        __builtin_amdgcn_s_setprio(1);
#pragma unroll
        for (int c = 0; c < 4; ++c) {
            const unsigned short* kbase = Ks + (c * 16 + ln16) * 128;
#pragma unroll
            for (int ds = 0; ds < 4; ++ds) {
                short8 kf = *(const short8*)(kbase + (((ds * 4 + quad) ^ lsw) << 3));
                sa[0][c] = __builtin_amdgcn_mfma_f32_16x16x32_bf16(qf[0][ds], kf, sa[0][c], 0, 0, 0);
                sa[1][c] = __builtin_amdgcn_mfma_f32_16x16x32_bf16(qf[1][ds], kf, sa[1][c], 0, 0, 0);
            }
        }
        __builtin_amdgcn_s_setprio(0);

        // ---- mask + online softmax + P->LDS, per subtile ----
#pragma unroll
        for (int s = 0; s < 2; ++s) {
            u64 ash[4];
#pragma unroll
            for (int r = 0; r < 4; ++r)
                ash[r] = allowed[wave * 32 + s * 16 + quad * 4 + r] >> ln16;
            float sc[4][4];
#pragma unroll
            for (int c = 0; c < 4; ++c)
#pragma unroll
                for (int r = 0; r < 4; ++r) {
                    bool ok = (ash[r] >> (c * 16)) & 1ull;
                    sc[c][r] = ok ? sa[s][c][r] : -__builtin_inff();
                }
            float mloc[4];
#pragma unroll
            for (int r = 0; r < 4; ++r) {
                float mx = fmaxf(fmaxf(sc[0][r], sc[1][r]), fmaxf(sc[2][r], sc[3][r]));
#pragma unroll
                for (int d = 8; d >= 1; d >>= 1) mx = fmaxf(mx, __shfl_xor(mx, d, 64));
                mloc[r] = mx;
            }
            // exact defer-rescale: skip alpha path if no row's max grew
            // (skipped ops are exactly *1.0 -> bit-identical).
            bool nd = (mloc[0] > m_run[s][0]) | (mloc[1] > m_run[s][1]) |
                      (mloc[2] > m_run[s][2]) | (mloc[3] > m_run[s][3]);
            if (__any((int)nd)) {
#pragma unroll
                for (int r = 0; r < 4; ++r) {
                    float mn = fmaxf(m_run[s][r], mloc[r]);
                    float al = __expf(m_run[s][r] - mn);
                    m_run[s][r] = mn;
                    l_run[s][r] *= al;
#pragma unroll
                    for (int n = 0; n < 8; ++n) o4[s][n][r] *= al;
                }
            }
#pragma unroll
            for (int r = 0; r < 4; ++r) {
                float su = 0.f;
                float pvr[4];
#pragma unroll
                for (int c = 0; c < 4; ++c) {
                    float p = __expf(sc[c][r] - m_run[s][r]);
                    pvr[c] = p;
                    su += p;
                }
#pragma unroll
                for (int c = 0; c < 4; ++c)
                    psw[s][(quad * 4 + r) * PS_STRIDE + c * 16 + ln16] = f2bf(pvr[c]);
#pragma unroll
                for (int d = 8; d >= 1; d >>= 1) su += __shfl_xor(su, d, 64);
                l_run[s][r] += su;
            }
        }
        asm volatile("" ::: "memory");   // order psw writes before reads (per-wave DS in-order)

        short8 pf[2][2];
#pragma unroll
        for (int s = 0; s < 2; ++s) {
            pf[s][0] = *(const short8*)&psw[s][ln16 * PS_STRIDE + quad * 8];
            pf[s][1] = *(const short8*)&psw[s][ln16 * PS_STRIDE + 32 + quad * 8];
        }

        // ---- O += P V, both subtiles share each V fragment ----
        __builtin_amdgcn_s_setprio(1);
#pragma unroll
        for (int n = 0; n < 8; ++n) {
            const unsigned short* vbase = Vt + (n * 16 + ln16) * 64;
            short8 vf0 = *(const short8*)(vbase + ((quad ^ lsw) << 3));
            short8 vf1 = *(const short8*)(vbase + (((quad + 4) ^ lsw) << 3));
            o4[0][n] = __builtin_amdgcn_mfma_f32_16x16x32_bf16(pf[0][0], vf0, o4[0][n], 0, 0, 0);
            o4[0][n] = __builtin_amdgcn_mfma_f32_16x16x32_bf16(pf[0][1], vf1, o4[0][n], 0, 0, 0);
            o4[1][n] = __builtin_amdgcn_mfma_f32_16x16x32_bf16(pf[1][0], vf0, o4[1][n], 0, 0, 0);
            o4[1][n] = __builtin_amdgcn_mfma_f32_16x16x32_bf16(pf[1][1], vf1, o4[1][n], 0, 0, 0);
        }
        __builtin_amdgcn_s_setprio(0);
    }

    // ---- write partial (O bf16, m, l) ----
    int pidx = h * NJOBS + job;
    unsigned short* pOp = pO + (size_t)pidx * (128 * DHEAD);
#pragma unroll
    for (int s = 0; s < 2; ++s)
#pragma unroll
        for (int r = 0; r < 4; ++r) {
            int row = wave * 32 + s * 16 + quad * 4 + r;
            if (ln16 == 0) {
                pm[pidx * 128 + row] = m_run[s][r];
                pl[pidx * 128 + row] = l_run[s][r];
            }
#pragma unroll
            for (int n = 0; n < 8; ++n)
                pOp[row * DHEAD + n * 16 + ln16] = f2bf(o4[s][n][r]);
        }
}

// ---------------------------------------------------------------------------
// Merge partials -> normalized output. 256 blocks (h,Q) x 256 threads.
// ---------------------------------------------------------------------------
__global__ __launch_bounds__(256) void merge_out(const unsigned short* __restrict__ pO,
                                                 const float* __restrict__ pm,
                                                 const float* __restrict__ pl,
                                                 float* __restrict__ out) {
    int b = blockIdx.x;
    int h = b >> 5, Q = b & 31;
    int t = threadIdx.x;
    int row = t >> 1, half = t & 1;
    int p0 = h * NJOBS + pBase[Q];
    int cnt = pCnt[Q];

    float mp[6], lp[6];
    float ms = NEGBIG;
    for (int p = 0; p < cnt; ++p) {
        mp[p] = pm[(p0 + p) * 128 + row];
        lp[p] = pl[(p0 + p) * 128 + row];
        ms = fmaxf(ms, mp[p]);
    }
    float denom = 0.f, w[6];
    for (int p = 0; p < cnt; ++p) {
        w[p] = __expf(mp[p] - ms);
        denom += w[p] * lp[p];
    }
    float invl = 1.0f / denom;

    float acc[64];
#pragma unroll
    for (int i = 0; i < 64; ++i) acc[i] = 0.f;
    for (int p = 0; p < cnt; ++p) {
        const unsigned short* Op = pO + (size_t)(p0 + p) * (128 * DHEAD) + row * DHEAD + half * 64;
        float wp = w[p];
#pragma unroll
        for (int g = 0; g < 8; ++g) {
            ushort4 u0 = ((const ushort4*)Op)[g * 2];
            ushort4 u1 = ((const ushort4*)Op)[g * 2 + 1];
            acc[g * 8 + 0] += wp * bf2f(u0.x); acc[g * 8 + 1] += wp * bf2f(u0.y);
            acc[g * 8 + 2] += wp * bf2f(u0.z); acc[g * 8 + 3] += wp * bf2f(u0.w);
            acc[g * 8 + 4] += wp * bf2f(u1.x); acc[g * 8 + 5] += wp * bf2f(u1.y);
            acc[g * 8 + 6] += wp * bf2f(u1.z); acc[g * 8 + 7] += wp * bf2f(u1.w);
        }
    }
    float* op = out + ((size_t)h * S_LEN + Q * 128 + row) * DHEAD + half * 64;
#pragma unroll
    for (int g = 0; g < 16; ++g) {
        float4 c;
        c.x = acc[g * 4 + 0] * invl; c.y = acc[g * 4 + 1] * invl;
        c.z = acc[g * 4 + 2] * invl; c.w = acc[g * 4 + 3] * invl;
        ((float4*)op)[g] = c;
    }
}

// ---------------------------------------------------------------------------
extern "C" void kernel_launch(void* const* d_in, const int* in_sizes, int n_in,
                              void* d_out, int out_size, void* d_ws, size_t ws_size,
                              hipStream_t stream) {
    const float* q = (const float*)d_in[0];
    const float* k = (const float*)d_in[1];
    const float* v = (const float*)d_in[2];
    float* out = (float*)d_out;

    unsigned* col_m  = (unsigned*)d_ws;                          // 1024 u32
    unsigned* diag_m = col_m + 1024;                             // 1024 u32
    float* m_all   = (float*)(diag_m + 1024);                    // 512 f32
    float* inv_all = m_all + 512;                                // 512 f32
    unsigned short* kbf  = (unsigned short*)(inv_all + 512);     // 4M bf16 (8 MB)
    unsigned short* vtbf = kbf + (size_t)NHEAD * S_LEN * DHEAD;  // 4M bf16 (8 MB)
    float* scores = (float*)(vtbf + (size_t)NHEAD * S_LEN * DHEAD);          // 8 MB
    unsigned short* pO = (unsigned short*)(scores + (size_t)NHEAD * LASTQ * S_LEN); // 29.1 MB
    float* pm = (float*)(pO + (size_t)8 * NJOBS * 128 * DHEAD);  // 888*128 f32
    float* pl = pm + 8 * NJOBS * 128;

    prep_score<<<2048, 256, 0, stream>>>(q, k, v, kbf, vtbf, scores);
    row_stats<<<NHEAD * LASTQ / 4, 256, 0, stream>>>(scores, m_all, inv_all);
    pattern_finish<<<NHEAD * 2, 1024, 0, stream>>>(scores, m_all, inv_all, col_m, diag_m);
    sparse_attn_mfma<<<NHEAD * NJOBS, 256, 0, stream>>>(q, kbf, vtbf, col_m, diag_m, pO, pm, pl);
    merge_out<<<NHEAD * 32, 256, 0, stream>>>(pO, pm, pl, out);
}

// Round 2
// 366.184 us; speedup vs baseline: 1.3317x; 1.3317x over previous
//
#include <hip/hip_runtime.h>
#include <hip/hip_bf16.h>
#include <math.h>

#define S_LEN 4096
#define DHEAD 128
#define NHEAD 8
#define LASTQ 64
#define V_TOPK 1024
#define S_TOPK 2048
#define FORCE_V 30
#define FORCE_S 100

#define SCALE 0.08838834764831845f
#define NEGBIG -3.0e38f

#define NJOBS 111   // split-K jobs per head (chunks of <=11 k-tiles)

typedef __attribute__((ext_vector_type(8))) short short8;
typedef __attribute__((ext_vector_type(4))) float floatx4;
typedef unsigned long long u64;

__device__ __forceinline__ unsigned short f2bf(float f) {
    unsigned u = __float_as_uint(f);
    unsigned r = (u + 0x7fffu + ((u >> 16) & 1u)) >> 16;   // RNE
    return (unsigned short)r;
}
__device__ __forceinline__ float bf2f(unsigned short s) {
    unsigned u = ((unsigned)s) << 16;
    return __uint_as_float(u);
}

// ---- split-K job tables: per head, q-block Q in [0,32) (128 rows each),
// k-range [K0,K1) in 64-key tiles; job id == partial index. ----
__device__ const short jobQ[NJOBS] = {
    0,1,2,3,4, 5,5, 6,6, 7,7, 8,8, 9,9, 10,10,
    11,11,11, 12,12,12, 13,13,13, 14,14,14, 15,15,15,
    16,16,16,16, 17,17,17,17, 18,18,18,18, 19,19,19,19, 20,20,20,20, 21,21,21,21,
    22,22,22,22,22, 23,23,23,23,23, 24,24,24,24,24, 25,25,25,25,25, 26,26,26,26,26,
    27,27,27,27,27,27, 28,28,28,28,28,28, 29,29,29,29,29,29, 30,30,30,30,30,30,
    31,31,31,31,31,31};
__device__ const short jobK0[NJOBS] = {
    0,0,0,0,0, 0,6, 0,7, 0,8, 0,9, 0,10, 0,11,
    0,8,16, 0,9,18, 0,10,19, 0,10,20, 0,11,22,
    0,9,18,26, 0,9,18,27, 0,10,20,29, 0,10,20,30, 0,11,22,32, 0,11,22,33,
    0,10,19,28,37, 0,10,20,30,39, 0,10,20,30,40, 0,11,22,32,42, 0,11,22,33,44,
    0,10,20,29,38,47, 0,10,20,30,40,49, 0,10,20,30,40,50, 0,11,22,32,42,52,
    0,11,22,33,44,54};
__device__ const short jobK1[NJOBS] = {
    2,4,6,8,10, 6,12, 7,14, 8,16, 9,18, 10,20, 11,22,
    8,16,24, 9,18,26, 10,19,28, 10,20,30, 11,22,32,
    9,18,26,34, 9,18,27,36, 10,20,29,38, 10,20,30,40, 11,22,32,42, 11,22,33,44,
    10,19,28,37,46, 10,20,30,39,48, 10,20,30,40,50, 11,22,32,42,52, 11,22,33,44,54,
    10,20,29,38,47,56, 10,20,30,40,49,58, 10,20,30,40,50,60, 11,22,32,42,52,62,
    11,22,33,44,54,64};
__device__ const short pBase[32] = {0,1,2,3,4,5,7,9,11,13,15,17,20,23,26,29,
                                    32,36,40,44,48,52,56,61,66,71,76,81,87,93,99,105};
__device__ const short pCnt[32]  = {1,1,1,1,1,2,2,2,2,2,2,3,3,3,3,3,
                                    4,4,4,4,4,4,5,5,5,5,5,6,6,6,6,6};

// ---------------------------------------------------------------------------
// Fused prep + score_qk (independent work, one launch):
//   blocks 0..511    : K fp32->bf16
//   blocks 512..1535 : V transpose -> Vt[h][d][s] bf16
//   blocks 1536..2047: scores[h][qi][j] for last-64 queries (fp32 topk-faithful)
// ---------------------------------------------------------------------------
__global__ __launch_bounds__(256) void prep_score(const float* __restrict__ q,
                                                  const float* __restrict__ k,
                                                  const float* __restrict__ v,
                                                  unsigned short* __restrict__ kbf,
                                                  unsigned short* __restrict__ vtbf,
                                                  float* __restrict__ scores) {
    int b = blockIdx.x, t = threadIdx.x;
    __shared__ __align__(16) float4 SH[64 * 32];   // 32 KB, aliased per branch

    if (b < 512) {
        const float4* src = (const float4*)k;
        int base = b * 2048;
#pragma unroll
        for (int i = 0; i < 8; ++i) {
            int idx = base + i * 256 + t;
            float4 val = src[idx];
            ushort4 o;
            o.x = f2bf(val.x); o.y = f2bf(val.y); o.z = f2bf(val.z); o.w = f2bf(val.w);
            ((ushort4*)kbf)[idx] = o;
        }
    } else if (b < 1536) {
        int bx = b - 512;
        int h  = bx >> 7;
        int rem = bx & 127;
        int d0 = (rem >> 6) * 64;
        int k0 = (rem & 63) * 64;
        unsigned short (*T)[72] = reinterpret_cast<unsigned short(*)[72]>(SH);
#pragma unroll
        for (int it = 0; it < 4; ++it) {
            int idx = t + it * 256;
            int r = idx >> 4, c4 = idx & 15;
            float4 val = *(const float4*)(v + ((size_t)(h * S_LEN) + k0 + r) * DHEAD + d0 + c4 * 4);
            T[c4 * 4 + 0][r] = f2bf(val.x);
            T[c4 * 4 + 1][r] = f2bf(val.y);
            T[c4 * 4 + 2][r] = f2bf(val.z);
            T[c4 * 4 + 3][r] = f2bf(val.w);
        }
        __syncthreads();
#pragma unroll
        for (int it = 0; it < 2; ++it) {
            int idx = t + it * 256;
            int r = idx >> 3, c8 = idx & 7;
            *(uint4*)(vtbf + ((size_t)h * DHEAD + d0 + r) * S_LEN + k0 + c8 * 8) = *(uint4*)&T[r][c8 * 8];
        }
    } else {
        int bx = b - 1536;
        int h  = bx >> 6;
        int kt = bx & 63;
        int jl = t >> 2, part = t & 3;
        int j  = kt * 64 + jl;

        float4* Qs = (float4*)SH;
        const float4* qbase = (const float4*)(q + ((size_t)h * S_LEN + (S_LEN - LASTQ)) * DHEAD);
        for (int idx = t; idx < 64 * 32; idx += 256) Qs[idx] = qbase[idx];
        __syncthreads();

        float4 kr[8];
        const float4* kp = (const float4*)(k + ((size_t)h * S_LEN + j) * DHEAD) + part * 8;
#pragma unroll
        for (int c = 0; c < 8; ++c) kr[c] = kp[c];

        float* sp = scores + (size_t)h * LASTQ * S_LEN + j;
#pragma unroll 4
        for (int qi = 0; qi < LASTQ; ++qi) {
            const float4* qp4 = Qs + qi * 32 + part * 8;
            float dot = 0.f;
#pragma unroll
            for (int c = 0; c < 8; ++c) {
                float4 a = qp4[c], bb = kr[c];
                dot += a.x * bb.x + a.y * bb.y + a.z * bb.z + a.w * bb.w;
            }
            dot += __shfl_xor(dot, 1, 64);
            dot += __shfl_xor(dot, 2, 64);
            if (part == 0) {
                int qpos = S_LEN - LASTQ + qi;
                sp[(size_t)qi * S_LEN] = (j <= qpos) ? dot * SCALE : NEGBIG;
            }
        }
    }
}

// ---------------------------------------------------------------------------
// P2a: per-row softmax stats (m, 1/sum). 512 rows, one wave per row.
// ---------------------------------------------------------------------------
__global__ __launch_bounds__(256) void row_stats(const float* __restrict__ scores,
                                                 float* __restrict__ m_out,
                                                 float* __restrict__ inv_out) {
    int row  = blockIdx.x * 4 + (threadIdx.x >> 6);
    int lane = threadIdx.x & 63;
    const float4* rp = (const float4*)(scores + (size_t)row * S_LEN);
    float mx = NEGBIG;
    for (int i = lane; i < S_LEN / 4; i += 64) {
        float4 s4 = rp[i];
        mx = fmaxf(mx, fmaxf(fmaxf(s4.x, s4.y), fmaxf(s4.z, s4.w)));
    }
#pragma unroll
    for (int d = 32; d >= 1; d >>= 1) mx = fmaxf(mx, __shfl_xor(mx, d, 64));
    float su = 0.f;
    for (int i = lane; i < S_LEN / 4; i += 64) {
        float4 s4 = rp[i];
        su += __expf(s4.x - mx) + __expf(s4.y - mx) + __expf(s4.z - mx) + __expf(s4.w - mx);
    }
#pragma unroll
    for (int d = 32; d >= 1; d >>= 1) su += __shfl_xor(su, d, 64);
    if (lane == 0) { m_out[row] = mx; inv_out[row] = 1.0f / su; }
}

// ---------------------------------------------------------------------------
// P2b+B fused: per (head, {vertical,slash}) accumulate scores + exact
// k-th-largest radix select -> membership bitmask. 16 blocks x 1024 threads.
// ---------------------------------------------------------------------------
__global__ __launch_bounds__(1024) void pattern_finish(const float* __restrict__ scores,
                                                       const float* __restrict__ m_all,
                                                       const float* __restrict__ inv_all,
                                                       unsigned* __restrict__ col_mask,
                                                       unsigned* __restrict__ diag_mask) {
    int h   = blockIdx.x >> 1;
    int sel = blockIdx.x & 1;
    int t = threadIdx.x;
    int kwant  = sel ? S_TOPK : V_TOPK;
    int forced = sel ? FORCE_S : FORCE_V;
    unsigned* dst = sel ? (diag_mask + h * 128) : (col_mask + h * 128);

    __shared__ float sm[LASTQ], sv[LASTQ];
    __shared__ unsigned keys[S_LEN];
    __shared__ int hist[256];
    __shared__ int sh_digit, sh_want;

    if (t < LASTQ) { sm[t] = m_all[h * LASTQ + t]; sv[t] = inv_all[h * LASTQ + t]; }
    __syncthreads();

    const float* S0 = scores + (size_t)h * LASTQ * S_LEN;
#pragma unroll
    for (int rep = 0; rep < 4; ++rep) {
        int j = rep * 1024 + t;
        float acc = 0.f;
        if (sel == 0) {
            for (int r = 0; r < LASTQ; ++r)
                acc += __expf(S0[(size_t)r * S_LEN + j] - sm[r]) * sv[r];
        } else {
            for (int r = 0; r < LASTQ; ++r) {
                int idx = (S_LEN - LASTQ) + r - j;
                if (idx >= 0)
                    acc += __expf(S0[(size_t)r * S_LEN + idx] - sm[r]) * sv[r];
            }
        }
        float f = (j < forced) ? __builtin_inff() : acc;
        unsigned u = __float_as_uint(f);
        u = (u & 0x80000000u) ? ~u : (u | 0x80000000u);
        keys[j] = u;
    }
    __syncthreads();

    unsigned prefix = 0;
    int want = kwant;
    for (int shift = 24; shift >= 0; shift -= 8) {
        if (t < 256) hist[t] = 0;
        __syncthreads();
        for (int j = t; j < S_LEN; j += 1024) {
            unsigned key = keys[j];
            bool match = (shift == 24) || (((key ^ prefix) >> (shift + 8)) == 0);
            if (match) atomicAdd(&hist[(key >> shift) & 255u], 1);
        }
        __syncthreads();
        if (t == 0) {
            int cum = 0, d = 255;
            for (; d >= 0; --d) {
                cum += hist[d];
                if (cum >= want) break;
            }
            sh_digit = d;
            sh_want  = want - (cum - hist[d]);
        }
        __syncthreads();
        prefix |= ((unsigned)sh_digit) << shift;
        want = sh_want;
        __syncthreads();
    }
    if (t < 128) {
        unsigned bits = 0;
        for (int b = 0; b < 32; ++b)
            if (keys[t * 32 + b] >= prefix) bits |= (1u << b);
        dst[t] = bits;
    }
}

// ---------------------------------------------------------------------------
// Phase C: MFMA flash attention, 128 q-rows per block, split-K jobs.
// (256,2): round-1's (256,3) forced VGPR to 84 -> accumulator spill to
// scratch (WRITE_SIZE 29MB->464MB, 109->285us). Cap must stay at 256.
// Keeps: T14 reg-prefetch async staging, XOR slot-swizzled unpadded Ks/Vt,
// s_setprio around MFMA clusters, exact defer-rescale.
// ---------------------------------------------------------------------------
#define PS_STRIDE 72

__global__ __launch_bounds__(256, 2) void sparse_attn_mfma(
        const float* __restrict__ q,
        const unsigned short* __restrict__ kbf,
        const unsigned short* __restrict__ vtbf,
        const unsigned* __restrict__ col_mask,
        const unsigned* __restrict__ diag_mask,
        unsigned short* __restrict__ pO, float* __restrict__ pm, float* __restrict__ pl) {
    int b = blockIdx.x;
    int h = b & 7;
    int job = b >> 3;                 // 0..110
    int Q  = jobQ[job];
    int k0 = jobK0[job];
    int k1 = jobK1[job];
    int i0 = Q * 128;
    int t    = threadIdx.x;
    int wave = t >> 6;
    int lane = t & 63;
    int ln16 = lane & 15;
    int quad = lane >> 4;
    int lsw  = ln16 & 7;              // row&7 for all LDS rows this lane touches

    // Unpadded tiles + XOR slot swizzle (16B slots, slot' = slot ^ (row&7)).
    __shared__ __align__(16) unsigned short Ks[64 * 128];
    __shared__ __align__(16) unsigned short Vt[128 * 64];
    __shared__ __align__(16) unsigned short Ps[8 * 16 * PS_STRIDE];
    __shared__ u64 allowed[128];
    __shared__ unsigned dmLDS[130];

    if (t < 130) dmLDS[t] = (t < 128) ? diag_mask[h * 128 + t] : 0u;

    // Q fragments for both 16-row subtiles (SCALE folded in), fp32 -> bf16
    short8 qf[2][4];
#pragma unroll
    for (int s = 0; s < 2; ++s) {
        int qrow = i0 + wave * 32 + s * 16 + ln16;
        const float* qp = q + ((size_t)h * S_LEN + qrow) * DHEAD;
#pragma unroll
        for (int ds = 0; ds < 4; ++ds) {
            int base = ds * 32 + quad * 8;
            float4 a = *(const float4*)(qp + base);
            float4 c = *(const float4*)(qp + base + 4);
            union { unsigned short u[8]; short8 v; } tmp;
            tmp.u[0] = f2bf(a.x * SCALE); tmp.u[1] = f2bf(a.y * SCALE);
            tmp.u[2] = f2bf(a.z * SCALE); tmp.u[3] = f2bf(a.w * SCALE);
            tmp.u[4] = f2bf(c.x * SCALE); tmp.u[5] = f2bf(c.y * SCALE);
            tmp.u[6] = f2bf(c.z * SCALE); tmp.u[7] = f2bf(c.w * SCALE);
            qf[s][ds] = tmp.v;
        }
    }

    floatx4 o4[2][8];
#pragma unroll
    for (int s = 0; s < 2; ++s)
#pragma unroll
        for (int n = 0; n < 8; ++n) o4[s][n] = (floatx4){0.f, 0.f, 0.f, 0.f};
    float m_run[2][4] = {{NEGBIG, NEGBIG, NEGBIG, NEGBIG}, {NEGBIG, NEGBIG, NEGBIG, NEGBIG}};
    float l_run[2][4] = {{0.f, 0.f, 0.f, 0.f}, {0.f, 0.f, 0.f, 0.f}};

    unsigned short* psw[2];
    psw[0] = Ps + (wave * 2 + 0) * 16 * PS_STRIDE;
    psw[1] = Ps + (wave * 2 + 1) * 16 * PS_STRIDE;

    const unsigned short* kgbase = kbf + (size_t)h * S_LEN * DHEAD;
    const unsigned short* vgbase = vtbf + (size_t)h * DHEAD * S_LEN;

    // T14 async-stage: prefetch next tile into regs while computing current.
    uint4 kreg[4], vreg[4];
    auto load_tile = [&](int j0_) {
#pragma unroll
        for (int it = 0; it < 4; ++it) {
            int idx = t + it * 256;
            kreg[it] = *(const uint4*)(kgbase + ((size_t)(j0_ + (idx >> 4))) * DHEAD + (idx & 15) * 8);
        }
#pragma unroll
        for (int it = 0; it < 4; ++it) {
            int idx = t + it * 256;
            vreg[it] = *(const uint4*)(vgbase + ((size_t)(idx >> 3)) * S_LEN + j0_ + (idx & 7) * 8);
        }
    };

    load_tile(k0 * 64);

    for (int jt = k0; jt < k1; ++jt) {
        int j0 = jt * 64;
        __syncthreads();   // previous iteration's LDS reads done

        // ---- write prefetched tile to LDS (swizzled) ----
#pragma unroll
        for (int it = 0; it < 4; ++it) {
            int idx = t + it * 256;
            int r = idx >> 4, c8 = idx & 15;
            *(uint4*)&Ks[r * 128 + ((c8 ^ (r & 7)) << 3)] = kreg[it];
        }
#pragma unroll
        for (int it = 0; it < 4; ++it) {
            int idx = t + it * 256;
            int r = idx >> 3, c8 = idx & 7;
            *(uint4*)&Vt[r * 64 + ((c8 ^ (r & 7)) << 3)] = vreg[it];
        }
        // ---- issue next tile's loads (latency hides under compute) ----
        if (jt + 1 < k1) load_tile(j0 + 64);

        // ---- per-row allowed bitmask (128 rows) ----
        if (t < 128) {
            int i = i0 + t;
            int off0 = i - j0;
            u64 a = 0;
            if (off0 >= 0) {
                u64 causal = (off0 >= 63) ? ~0ull : ((1ull << (off0 + 1)) - 1ull);
                u64 cwv = ((u64)col_mask[h * 128 + (j0 >> 5) + 1] << 32) |
                          (u64)col_mask[h * 128 + (j0 >> 5)];
                int sb = off0 - 63;
                u64 V;
                if (sb >= 0) {
                    int w = sb >> 5, sh = sb & 31;
                    u64 lo = ((u64)dmLDS[w + 1] << 32) | (u64)dmLDS[w];
                    u64 hi = (u64)dmLDS[w + 2];
                    V = (lo >> sh) | (sh ? (hi << (64 - sh)) : 0ull);
                } else {
                    u64 w0 = ((u64)dmLDS[1] << 32) | (u64)dmLDS[0];
                    V = w0 << (-sb);
                }
                a = (cwv | __brevll(V)) & causal;
            }
            allowed[t] = a;
        }
        __syncthreads();

        // ---- S = Q K^T, both subtiles share each K fragment ----
        floatx4 sa[2][4];
#pragma unroll
        for (int s = 0; s < 2; ++s)
#pragma unroll
            for (int c = 0; c < 4; ++c) sa[s][c] = (floatx4){0.f, 0.f, 0.f, 0.f};
        __builtin_amdgcn_s_setprio(1);
#pragma unroll
        for (int c = 0; c < 4; ++c) {
            const unsigned short* kbase = Ks + (c * 16 + ln16) * 128;
#pragma unroll
            for (int ds = 0; ds < 4; ++ds) {
                short8 kf = *(const short8*)(kbase + (((ds * 4 + quad) ^ lsw) << 3));
                sa[0][c] = __builtin_amdgcn_mfma_f32_16x16x32_bf16(qf[0][ds], kf, sa[0][c], 0, 0, 0);
                sa[1][c] = __builtin_amdgcn_mfma_f32_16x16x32_bf16(qf[1][ds], kf, sa[1][c], 0, 0, 0);
            }
        }
        __builtin_amdgcn_s_setprio(0);

        // ---- mask + online softmax + P->LDS, per subtile ----
#pragma unroll
        for (int s = 0; s < 2; ++s) {
            u64 ash[4];
#pragma unroll
            for (int r = 0; r < 4; ++r)
                ash[r] = allowed[wave * 32 + s * 16 + quad * 4 + r] >> ln16;
            float sc[4][4];
#pragma unroll
            for (int c = 0; c < 4; ++c)
#pragma unroll
                for (int r = 0; r < 4; ++r) {
                    bool ok = (ash[r] >> (c * 16)) & 1ull;
                    sc[c][r] = ok ? sa[s][c][r] : -__builtin_inff();
                }
            float mloc[4];
#pragma unroll
            for (int r = 0; r < 4; ++r) {
                float mx = fmaxf(fmaxf(sc[0][r], sc[1][r]), fmaxf(sc[2][r], sc[3][r]));
#pragma unroll
                for (int d = 8; d >= 1; d >>= 1) mx = fmaxf(mx, __shfl_xor(mx, d, 64));
                mloc[r] = mx;
            }
            // exact defer-rescale: skip alpha path if no row's max grew
            // (skipped ops are exactly *1.0 -> bit-identical).
            bool nd = (mloc[0] > m_run[s][0]) | (mloc[1] > m_run[s][1]) |
                      (mloc[2] > m_run[s][2]) | (mloc[3] > m_run[s][3]);
            if (__any((int)nd)) {
#pragma unroll
                for (int r = 0; r < 4; ++r) {
                    float mn = fmaxf(m_run[s][r], mloc[r]);
                    float al = __expf(m_run[s][r] - mn);
                    m_run[s][r] = mn;
                    l_run[s][r] *= al;
#pragma unroll
                    for (int n = 0; n < 8; ++n) o4[s][n][r] *= al;
                }
            }
#pragma unroll
            for (int r = 0; r < 4; ++r) {
                float su = 0.f;
                float pvr[4];
#pragma unroll
                for (int c = 0; c < 4; ++c) {
                    float p = __expf(sc[c][r] - m_run[s][r]);
                    pvr[c] = p;
                    su += p;
                }
#pragma unroll
                for (int c = 0; c < 4; ++c)
                    psw[s][(quad * 4 + r) * PS_STRIDE + c * 16 + ln16] = f2bf(pvr[c]);
#pragma unroll
                for (int d = 8; d >= 1; d >>= 1) su += __shfl_xor(su, d, 64);
                l_run[s][r] += su;
            }
        }
        asm volatile("" ::: "memory");   // order psw writes before reads (per-wave DS in-order)

        short8 pf[2][2];
#pragma unroll
        for (int s = 0; s < 2; ++s) {
            pf[s][0] = *(const short8*)&psw[s][ln16 * PS_STRIDE + quad * 8];
            pf[s][1] = *(const short8*)&psw[s][ln16 * PS_STRIDE + 32 + quad * 8];
        }

        // ---- O += P V, both subtiles share each V fragment ----
        __builtin_amdgcn_s_setprio(1);
#pragma unroll
        for (int n = 0; n < 8; ++n) {
            const unsigned short* vbase = Vt + (n * 16 + ln16) * 64;
            short8 vf0 = *(const short8*)(vbase + ((quad ^ lsw) << 3));
            short8 vf1 = *(const short8*)(vbase + (((quad + 4) ^ lsw) << 3));
            o4[0][n] = __builtin_amdgcn_mfma_f32_16x16x32_bf16(pf[0][0], vf0, o4[0][n], 0, 0, 0);
            o4[0][n] = __builtin_amdgcn_mfma_f32_16x16x32_bf16(pf[0][1], vf1, o4[0][n], 0, 0, 0);
            o4[1][n] = __builtin_amdgcn_mfma_f32_16x16x32_bf16(pf[1][0], vf0, o4[1][n], 0, 0, 0);
            o4[1][n] = __builtin_amdgcn_mfma_f32_16x16x32_bf16(pf[1][1], vf1, o4[1][n], 0, 0, 0);
        }
        __builtin_amdgcn_s_setprio(0);
    }

    // ---- write partial (O bf16, m, l) ----
    int pidx = h * NJOBS + job;
    unsigned short* pOp = pO + (size_t)pidx * (128 * DHEAD);
#pragma unroll
    for (int s = 0; s < 2; ++s)
#pragma unroll
        for (int r = 0; r < 4; ++r) {
            int row = wave * 32 + s * 16 + quad * 4 + r;
            if (ln16 == 0) {
                pm[pidx * 128 + row] = m_run[s][r];
                pl[pidx * 128 + row] = l_run[s][r];
            }
#pragma unroll
            for (int n = 0; n < 8; ++n)
                pOp[row * DHEAD + n * 16 + ln16] = f2bf(o4[s][n][r]);
        }
}

// ---------------------------------------------------------------------------
// Merge partials -> normalized output. 256 blocks (h,Q) x 256 threads.
// ---------------------------------------------------------------------------
__global__ __launch_bounds__(256) void merge_out(const unsigned short* __restrict__ pO,
                                                 const float* __restrict__ pm,
                                                 const float* __restrict__ pl,
                                                 float* __restrict__ out) {
    int b = blockIdx.x;
    int h = b >> 5, Q = b & 31;
    int t = threadIdx.x;
    int row = t >> 1, half = t & 1;
    int p0 = h * NJOBS + pBase[Q];
    int cnt = pCnt[Q];

    float mp[6], lp[6];
    float ms = NEGBIG;
    for (int p = 0; p < cnt; ++p) {
        mp[p] = pm[(p0 + p) * 128 + row];
        lp[p] = pl[(p0 + p) * 128 + row];
        ms = fmaxf(ms, mp[p]);
    }
    float denom = 0.f, w[6];
    for (int p = 0; p < cnt; ++p) {
        w[p] = __expf(mp[p] - ms);
        denom += w[p] * lp[p];
    }
    float invl = 1.0f / denom;

    float acc[64];
#pragma unroll
    for (int i = 0; i < 64; ++i) acc[i] = 0.f;
    for (int p = 0; p < cnt; ++p) {
        const unsigned short* Op = pO + (size_t)(p0 + p) * (128 * DHEAD) + row * DHEAD + half * 64;
        float wp = w[p];
#pragma unroll
        for (int g = 0; g < 8; ++g) {
            ushort4 u0 = ((const ushort4*)Op)[g * 2];
            ushort4 u1 = ((const ushort4*)Op)[g * 2 + 1];
            acc[g * 8 + 0] += wp * bf2f(u0.x); acc[g * 8 + 1] += wp * bf2f(u0.y);
            acc[g * 8 + 2] += wp * bf2f(u0.z); acc[g * 8 + 3] += wp * bf2f(u0.w);
            acc[g * 8 + 4] += wp * bf2f(u1.x); acc[g * 8 + 5] += wp * bf2f(u1.y);
            acc[g * 8 + 6] += wp * bf2f(u1.z); acc[g * 8 + 7] += wp * bf2f(u1.w);
        }
    }
    float* op = out + ((size_t)h * S_LEN + Q * 128 + row) * DHEAD + half * 64;
#pragma unroll
    for (int g = 0; g < 16; ++g) {
        float4 c;
        c.x = acc[g * 4 + 0] * invl; c.y = acc[g * 4 + 1] * invl;
        c.z = acc[g * 4 + 2] * invl; c.w = acc[g * 4 + 3] * invl;
        ((float4*)op)[g] = c;
    }
}

// ---------------------------------------------------------------------------
extern "C" void kernel_launch(void* const* d_in, const int* in_sizes, int n_in,
                              void* d_out, int out_size, void* d_ws, size_t ws_size,
                              hipStream_t stream) {
    const float* q = (const float*)d_in[0];
    const float* k = (const float*)d_in[1];
    const float* v = (const float*)d_in[2];
    float* out = (float*)d_out;

    unsigned* col_m  = (unsigned*)d_ws;                          // 1024 u32
    unsigned* diag_m = col_m + 1024;                             // 1024 u32
    float* m_all   = (float*)(diag_m + 1024);                    // 512 f32
    float* inv_all = m_all + 512;                                // 512 f32
    unsigned short* kbf  = (unsigned short*)(inv_all + 512);     // 4M bf16 (8 MB)
    unsigned short* vtbf = kbf + (size_t)NHEAD * S_LEN * DHEAD;  // 4M bf16 (8 MB)
    float* scores = (float*)(vtbf + (size_t)NHEAD * S_LEN * DHEAD);          // 8 MB
    unsigned short* pO = (unsigned short*)(scores + (size_t)NHEAD * LASTQ * S_LEN); // 29.1 MB
    float* pm = (float*)(pO + (size_t)8 * NJOBS * 128 * DHEAD);  // 888*128 f32
    float* pl = pm + 8 * NJOBS * 128;

    prep_score<<<2048, 256, 0, stream>>>(q, k, v, kbf, vtbf, scores);
    row_stats<<<NHEAD * LASTQ / 4, 256, 0, stream>>>(scores, m_all, inv_all);
    pattern_finish<<<NHEAD * 2, 1024, 0, stream>>>(scores, m_all, inv_all, col_m, diag_m);
    sparse_attn_mfma<<<NHEAD * NJOBS, 256, 0, stream>>>(q, kbf, vtbf, col_m, diag_m, pO, pm, pl);
    merge_out<<<NHEAD * 32, 256, 0, stream>>>(pO, pm, pl, out);
}

// Round 3
// 308.736 us; speedup vs baseline: 1.5794x; 1.1861x over previous
//
#include <hip/hip_runtime.h>
#include <hip/hip_bf16.h>
#include <math.h>

#define S_LEN 4096
#define DHEAD 128
#define NHEAD 8
#define LASTQ 64
#define V_TOPK 1024
#define S_TOPK 2048
#define FORCE_V 30
#define FORCE_S 100

#define SCALE 0.08838834764831845f
#define NEGBIG -3.0e38f

#define NJOBS 111   // split-K jobs per head (chunks of <=11 k-tiles)

typedef __attribute__((ext_vector_type(8))) short short8;
typedef __attribute__((ext_vector_type(4))) float floatx4;
typedef unsigned long long u64;

__device__ __forceinline__ unsigned short f2bf(float f) {
    unsigned u = __float_as_uint(f);
    unsigned r = (u + 0x7fffu + ((u >> 16) & 1u)) >> 16;   // RNE
    return (unsigned short)r;
}
__device__ __forceinline__ float bf2f(unsigned short s) {
    unsigned u = ((unsigned)s) << 16;
    return __uint_as_float(u);
}

// ---- split-K job tables: per head, q-block Q in [0,32) (128 rows each),
// k-range [K0,K1) in 64-key tiles; job id == partial index. ----
__device__ const short jobQ[NJOBS] = {
    0,1,2,3,4, 5,5, 6,6, 7,7, 8,8, 9,9, 10,10,
    11,11,11, 12,12,12, 13,13,13, 14,14,14, 15,15,15,
    16,16,16,16, 17,17,17,17, 18,18,18,18, 19,19,19,19, 20,20,20,20, 21,21,21,21,
    22,22,22,22,22, 23,23,23,23,23, 24,24,24,24,24, 25,25,25,25,25, 26,26,26,26,26,
    27,27,27,27,27,27, 28,28,28,28,28,28, 29,29,29,29,29,29, 30,30,30,30,30,30,
    31,31,31,31,31,31};
__device__ const short jobK0[NJOBS] = {
    0,0,0,0,0, 0,6, 0,7, 0,8, 0,9, 0,10, 0,11,
    0,8,16, 0,9,18, 0,10,19, 0,10,20, 0,11,22,
    0,9,18,26, 0,9,18,27, 0,10,20,29, 0,10,20,30, 0,11,22,32, 0,11,22,33,
    0,10,19,28,37, 0,10,20,30,39, 0,10,20,30,40, 0,11,22,32,42, 0,11,22,33,44,
    0,10,20,29,38,47, 0,10,20,30,40,49, 0,10,20,30,40,50, 0,11,22,32,42,52,
    0,11,22,33,44,54};
__device__ const short jobK1[NJOBS] = {
    2,4,6,8,10, 6,12, 7,14, 8,16, 9,18, 10,20, 11,22,
    8,16,24, 9,18,26, 10,19,28, 10,20,30, 11,22,32,
    9,18,26,34, 9,18,27,36, 10,20,29,38, 10,20,30,40, 11,22,32,42, 11,22,33,44,
    10,19,28,37,46, 10,20,30,39,48, 10,20,30,40,50, 11,22,32,42,52, 11,22,33,44,54,
    10,20,29,38,47,56, 10,20,30,40,49,58, 10,20,30,40,50,60, 11,22,32,42,52,62,
    11,22,33,44,54,64};
__device__ const short pBase[32] = {0,1,2,3,4,5,7,9,11,13,15,17,20,23,26,29,
                                    32,36,40,44,48,52,56,61,66,71,76,81,87,93,99,105};
__device__ const short pCnt[32]  = {1,1,1,1,1,2,2,2,2,2,2,3,3,3,3,3,
                                    4,4,4,4,4,4,5,5,5,5,5,6,6,6,6,6};

// ---------------------------------------------------------------------------
// Fused prep + score_qk (independent work, one launch):
//   blocks 0..511    : K fp32->bf16
//   blocks 512..1535 : V transpose -> Vt[h][d][s] bf16
//   blocks 1536..2047: scores[h][qi][j] for last-64 queries (fp32 topk-faithful)
// ---------------------------------------------------------------------------
__global__ __launch_bounds__(256) void prep_score(const float* __restrict__ q,
                                                  const float* __restrict__ k,
                                                  const float* __restrict__ v,
                                                  unsigned short* __restrict__ kbf,
                                                  unsigned short* __restrict__ vtbf,
                                                  float* __restrict__ scores) {
    int b = blockIdx.x, t = threadIdx.x;
    __shared__ __align__(16) float4 SH[64 * 32];   // 32 KB, aliased per branch

    if (b < 512) {
        const float4* src = (const float4*)k;
        int base = b * 2048;
#pragma unroll
        for (int i = 0; i < 8; ++i) {
            int idx = base + i * 256 + t;
            float4 val = src[idx];
            ushort4 o;
            o.x = f2bf(val.x); o.y = f2bf(val.y); o.z = f2bf(val.z); o.w = f2bf(val.w);
            ((ushort4*)kbf)[idx] = o;
        }
    } else if (b < 1536) {
        int bx = b - 512;
        int h  = bx >> 7;
        int rem = bx & 127;
        int d0 = (rem >> 6) * 64;
        int k0 = (rem & 63) * 64;
        unsigned short (*T)[72] = reinterpret_cast<unsigned short(*)[72]>(SH);
#pragma unroll
        for (int it = 0; it < 4; ++it) {
            int idx = t + it * 256;
            int r = idx >> 4, c4 = idx & 15;
            float4 val = *(const float4*)(v + ((size_t)(h * S_LEN) + k0 + r) * DHEAD + d0 + c4 * 4);
            T[c4 * 4 + 0][r] = f2bf(val.x);
            T[c4 * 4 + 1][r] = f2bf(val.y);
            T[c4 * 4 + 2][r] = f2bf(val.z);
            T[c4 * 4 + 3][r] = f2bf(val.w);
        }
        __syncthreads();
#pragma unroll
        for (int it = 0; it < 2; ++it) {
            int idx = t + it * 256;
            int r = idx >> 3, c8 = idx & 7;
            *(uint4*)(vtbf + ((size_t)h * DHEAD + d0 + r) * S_LEN + k0 + c8 * 8) = *(uint4*)&T[r][c8 * 8];
        }
    } else {
        int bx = b - 1536;
        int h  = bx >> 6;
        int kt = bx & 63;
        int jl = t >> 2, part = t & 3;
        int j  = kt * 64 + jl;

        float4* Qs = (float4*)SH;
        const float4* qbase = (const float4*)(q + ((size_t)h * S_LEN + (S_LEN - LASTQ)) * DHEAD);
        for (int idx = t; idx < 64 * 32; idx += 256) Qs[idx] = qbase[idx];
        __syncthreads();

        float4 kr[8];
        const float4* kp = (const float4*)(k + ((size_t)h * S_LEN + j) * DHEAD) + part * 8;
#pragma unroll
        for (int c = 0; c < 8; ++c) kr[c] = kp[c];

        float* sp = scores + (size_t)h * LASTQ * S_LEN + j;
#pragma unroll 4
        for (int qi = 0; qi < LASTQ; ++qi) {
            const float4* qp4 = Qs + qi * 32 + part * 8;
            float dot = 0.f;
#pragma unroll
            for (int c = 0; c < 8; ++c) {
                float4 a = qp4[c], bb = kr[c];
                dot += a.x * bb.x + a.y * bb.y + a.z * bb.z + a.w * bb.w;
            }
            dot += __shfl_xor(dot, 1, 64);
            dot += __shfl_xor(dot, 2, 64);
            if (part == 0) {
                int qpos = S_LEN - LASTQ + qi;
                sp[(size_t)qi * S_LEN] = (j <= qpos) ? dot * SCALE : NEGBIG;
            }
        }
    }
}

// ---------------------------------------------------------------------------
// P2a: per-row softmax stats (m, 1/sum). 512 rows, one wave per row.
// ---------------------------------------------------------------------------
__global__ __launch_bounds__(256) void row_stats(const float* __restrict__ scores,
                                                 float* __restrict__ m_out,
                                                 float* __restrict__ inv_out) {
    int row  = blockIdx.x * 4 + (threadIdx.x >> 6);
    int lane = threadIdx.x & 63;
    const float4* rp = (const float4*)(scores + (size_t)row * S_LEN);
    float mx = NEGBIG;
    for (int i = lane; i < S_LEN / 4; i += 64) {
        float4 s4 = rp[i];
        mx = fmaxf(mx, fmaxf(fmaxf(s4.x, s4.y), fmaxf(s4.z, s4.w)));
    }
#pragma unroll
    for (int d = 32; d >= 1; d >>= 1) mx = fmaxf(mx, __shfl_xor(mx, d, 64));
    float su = 0.f;
    for (int i = lane; i < S_LEN / 4; i += 64) {
        float4 s4 = rp[i];
        su += __expf(s4.x - mx) + __expf(s4.y - mx) + __expf(s4.z - mx) + __expf(s4.w - mx);
    }
#pragma unroll
    for (int d = 32; d >= 1; d >>= 1) su += __shfl_xor(su, d, 64);
    if (lane == 0) { m_out[row] = mx; inv_out[row] = 1.0f / su; }
}

// ---------------------------------------------------------------------------
// P2b+B fused: per (head, {vertical,slash}) accumulate scores + exact
// k-th-largest radix select -> membership bitmask. 16 blocks x 1024 threads.
// ---------------------------------------------------------------------------
__global__ __launch_bounds__(1024) void pattern_finish(const float* __restrict__ scores,
                                                       const float* __restrict__ m_all,
                                                       const float* __restrict__ inv_all,
                                                       unsigned* __restrict__ col_mask,
                                                       unsigned* __restrict__ diag_mask) {
    int h   = blockIdx.x >> 1;
    int sel = blockIdx.x & 1;
    int t = threadIdx.x;
    int kwant  = sel ? S_TOPK : V_TOPK;
    int forced = sel ? FORCE_S : FORCE_V;
    unsigned* dst = sel ? (diag_mask + h * 128) : (col_mask + h * 128);

    __shared__ float sm[LASTQ], sv[LASTQ];
    __shared__ unsigned keys[S_LEN];
    __shared__ int hist[256];
    __shared__ int sh_digit, sh_want;

    if (t < LASTQ) { sm[t] = m_all[h * LASTQ + t]; sv[t] = inv_all[h * LASTQ + t]; }
    __syncthreads();

    const float* S0 = scores + (size_t)h * LASTQ * S_LEN;
#pragma unroll
    for (int rep = 0; rep < 4; ++rep) {
        int j = rep * 1024 + t;
        float acc = 0.f;
        if (sel == 0) {
            for (int r = 0; r < LASTQ; ++r)
                acc += __expf(S0[(size_t)r * S_LEN + j] - sm[r]) * sv[r];
        } else {
            for (int r = 0; r < LASTQ; ++r) {
                int idx = (S_LEN - LASTQ) + r - j;
                if (idx >= 0)
                    acc += __expf(S0[(size_t)r * S_LEN + idx] - sm[r]) * sv[r];
            }
        }
        float f = (j < forced) ? __builtin_inff() : acc;
        unsigned u = __float_as_uint(f);
        u = (u & 0x80000000u) ? ~u : (u | 0x80000000u);
        keys[j] = u;
    }
    __syncthreads();

    unsigned prefix = 0;
    int want = kwant;
    for (int shift = 24; shift >= 0; shift -= 8) {
        if (t < 256) hist[t] = 0;
        __syncthreads();
        for (int j = t; j < S_LEN; j += 1024) {
            unsigned key = keys[j];
            bool match = (shift == 24) || (((key ^ prefix) >> (shift + 8)) == 0);
            if (match) atomicAdd(&hist[(key >> shift) & 255u], 1);
        }
        __syncthreads();
        if (t == 0) {
            int cum = 0, d = 255;
            for (; d >= 0; --d) {
                cum += hist[d];
                if (cum >= want) break;
            }
            sh_digit = d;
            sh_want  = want - (cum - hist[d]);
        }
        __syncthreads();
        prefix |= ((unsigned)sh_digit) << shift;
        want = sh_want;
        __syncthreads();
    }
    if (t < 128) {
        unsigned bits = 0;
        for (int b = 0; b < 32; ++b)
            if (keys[t * 32 + b] >= prefix) bits |= (1u << b);
        dst[t] = bits;
    }
}

// ---------------------------------------------------------------------------
// Phase C: MFMA flash attention, 128 q-rows per block, split-K jobs.
// History: (256,3) forced VGPR->84, spilled (464MB scratch). (256,2)+lambda
// prefetch: kreg/vreg arrays captured by-ref in a lambda -> address taken ->
// alloca survives -> scratch (232MB write, VGPR=108). Fix: NAMED scalar
// uint4 prefetch registers, no arrays, no lambda.
// Keeps: XOR slot-swizzled unpadded Ks/Vt, s_setprio, exact defer-rescale.
// ---------------------------------------------------------------------------
#define PS_STRIDE 72

__global__ __launch_bounds__(256, 2) void sparse_attn_mfma(
        const float* __restrict__ q,
        const unsigned short* __restrict__ kbf,
        const unsigned short* __restrict__ vtbf,
        const unsigned* __restrict__ col_mask,
        const unsigned* __restrict__ diag_mask,
        unsigned short* __restrict__ pO, float* __restrict__ pm, float* __restrict__ pl) {
    int b = blockIdx.x;
    int h = b & 7;
    int job = b >> 3;                 // 0..110
    int Q  = jobQ[job];
    int k0 = jobK0[job];
    int k1 = jobK1[job];
    int i0 = Q * 128;
    int t    = threadIdx.x;
    int wave = t >> 6;
    int lane = t & 63;
    int ln16 = lane & 15;
    int quad = lane >> 4;
    int lsw  = ln16 & 7;              // row&7 for all LDS rows this lane touches

    // Unpadded tiles + XOR slot swizzle (16B slots, slot' = slot ^ (row&7)).
    __shared__ __align__(16) unsigned short Ks[64 * 128];
    __shared__ __align__(16) unsigned short Vt[128 * 64];
    __shared__ __align__(16) unsigned short Ps[8 * 16 * PS_STRIDE];
    __shared__ u64 allowed[128];
    __shared__ unsigned dmLDS[130];

    if (t < 130) dmLDS[t] = (t < 128) ? diag_mask[h * 128 + t] : 0u;

    // ---- per-thread staging offsets (pure scalars, computed once) ----
    const int ti0 = t, ti1 = t + 256, ti2 = t + 512, ti3 = t + 768;
    // K tile: row = idx>>4 in [0,64), col8 = idx&15; global elem off / LDS elem off
    const int kgo0 = (ti0 >> 4) * DHEAD + (ti0 & 15) * 8;
    const int kgo1 = (ti1 >> 4) * DHEAD + (ti1 & 15) * 8;
    const int kgo2 = (ti2 >> 4) * DHEAD + (ti2 & 15) * 8;
    const int kgo3 = (ti3 >> 4) * DHEAD + (ti3 & 15) * 8;
    const int kso0 = (ti0 >> 4) * 128 + (((ti0 & 15) ^ ((ti0 >> 4) & 7)) << 3);
    const int kso1 = (ti1 >> 4) * 128 + (((ti1 & 15) ^ ((ti1 >> 4) & 7)) << 3);
    const int kso2 = (ti2 >> 4) * 128 + (((ti2 & 15) ^ ((ti2 >> 4) & 7)) << 3);
    const int kso3 = (ti3 >> 4) * 128 + (((ti3 & 15) ^ ((ti3 >> 4) & 7)) << 3);
    // V tile: row = idx>>3 in [0,128), col8 = idx&7
    const int vgo0 = (ti0 >> 3) * S_LEN + (ti0 & 7) * 8;
    const int vgo1 = (ti1 >> 3) * S_LEN + (ti1 & 7) * 8;
    const int vgo2 = (ti2 >> 3) * S_LEN + (ti2 & 7) * 8;
    const int vgo3 = (ti3 >> 3) * S_LEN + (ti3 & 7) * 8;
    const int vso0 = (ti0 >> 3) * 64 + (((ti0 & 7) ^ ((ti0 >> 3) & 7)) << 3);
    const int vso1 = (ti1 >> 3) * 64 + (((ti1 & 7) ^ ((ti1 >> 3) & 7)) << 3);
    const int vso2 = (ti2 >> 3) * 64 + (((ti2 & 7) ^ ((ti2 >> 3) & 7)) << 3);
    const int vso3 = (ti3 >> 3) * 64 + (((ti3 & 7) ^ ((ti3 >> 3) & 7)) << 3);

    // Q fragments for both 16-row subtiles (SCALE folded in), fp32 -> bf16
    short8 qf[2][4];
#pragma unroll
    for (int s = 0; s < 2; ++s) {
        int qrow = i0 + wave * 32 + s * 16 + ln16;
        const float* qp = q + ((size_t)h * S_LEN + qrow) * DHEAD;
#pragma unroll
        for (int ds = 0; ds < 4; ++ds) {
            int base = ds * 32 + quad * 8;
            float4 a = *(const float4*)(qp + base);
            float4 c = *(const float4*)(qp + base + 4);
            union { unsigned short u[8]; short8 v; } tmp;
            tmp.u[0] = f2bf(a.x * SCALE); tmp.u[1] = f2bf(a.y * SCALE);
            tmp.u[2] = f2bf(a.z * SCALE); tmp.u[3] = f2bf(a.w * SCALE);
            tmp.u[4] = f2bf(c.x * SCALE); tmp.u[5] = f2bf(c.y * SCALE);
            tmp.u[6] = f2bf(c.z * SCALE); tmp.u[7] = f2bf(c.w * SCALE);
            qf[s][ds] = tmp.v;
        }
    }

    floatx4 o4[2][8];
#pragma unroll
    for (int s = 0; s < 2; ++s)
#pragma unroll
        for (int n = 0; n < 8; ++n) o4[s][n] = (floatx4){0.f, 0.f, 0.f, 0.f};
    float m_run[2][4] = {{NEGBIG, NEGBIG, NEGBIG, NEGBIG}, {NEGBIG, NEGBIG, NEGBIG, NEGBIG}};
    float l_run[2][4] = {{0.f, 0.f, 0.f, 0.f}, {0.f, 0.f, 0.f, 0.f}};

    unsigned short* psw[2];
    psw[0] = Ps + (wave * 2 + 0) * 16 * PS_STRIDE;
    psw[1] = Ps + (wave * 2 + 1) * 16 * PS_STRIDE;

    const unsigned short* kgbase = kbf + (size_t)h * S_LEN * DHEAD;
    const unsigned short* vgbase = vtbf + (size_t)h * DHEAD * S_LEN;

    // T14 prefetch state: NAMED uint4 scalars (never an array, never a lambda
    // -> guaranteed VGPRs, no scratch).
    uint4 ka0, ka1, ka2, ka3, va0, va1, va2, va3;
    {
        const unsigned short* kg = kgbase + (size_t)(k0 * 64) * DHEAD;
        const unsigned short* vg = vgbase + k0 * 64;
        ka0 = *(const uint4*)(kg + kgo0); ka1 = *(const uint4*)(kg + kgo1);
        ka2 = *(const uint4*)(kg + kgo2); ka3 = *(const uint4*)(kg + kgo3);
        va0 = *(const uint4*)(vg + vgo0); va1 = *(const uint4*)(vg + vgo1);
        va2 = *(const uint4*)(vg + vgo2); va3 = *(const uint4*)(vg + vgo3);
    }

    for (int jt = k0; jt < k1; ++jt) {
        int j0 = jt * 64;
        __syncthreads();   // previous iteration's LDS reads done

        // ---- write prefetched tile to LDS (swizzled) ----
        *(uint4*)&Ks[kso0] = ka0; *(uint4*)&Ks[kso1] = ka1;
        *(uint4*)&Ks[kso2] = ka2; *(uint4*)&Ks[kso3] = ka3;
        *(uint4*)&Vt[vso0] = va0; *(uint4*)&Vt[vso1] = va1;
        *(uint4*)&Vt[vso2] = va2; *(uint4*)&Vt[vso3] = va3;

        // ---- issue next tile's loads (latency hides under compute) ----
        if (jt + 1 < k1) {
            const unsigned short* kg = kgbase + (size_t)(j0 + 64) * DHEAD;
            const unsigned short* vg = vgbase + (j0 + 64);
            ka0 = *(const uint4*)(kg + kgo0); ka1 = *(const uint4*)(kg + kgo1);
            ka2 = *(const uint4*)(kg + kgo2); ka3 = *(const uint4*)(kg + kgo3);
            va0 = *(const uint4*)(vg + vgo0); va1 = *(const uint4*)(vg + vgo1);
            va2 = *(const uint4*)(vg + vgo2); va3 = *(const uint4*)(vg + vgo3);
        }

        // ---- per-row allowed bitmask (128 rows) ----
        if (t < 128) {
            int i = i0 + t;
            int off0 = i - j0;
            u64 a = 0;
            if (off0 >= 0) {
                u64 causal = (off0 >= 63) ? ~0ull : ((1ull << (off0 + 1)) - 1ull);
                u64 cwv = ((u64)col_mask[h * 128 + (j0 >> 5) + 1] << 32) |
                          (u64)col_mask[h * 128 + (j0 >> 5)];
                int sb = off0 - 63;
                u64 V;
                if (sb >= 0) {
                    int w = sb >> 5, sh = sb & 31;
                    u64 lo = ((u64)dmLDS[w + 1] << 32) | (u64)dmLDS[w];
                    u64 hi = (u64)dmLDS[w + 2];
                    V = (lo >> sh) | (sh ? (hi << (64 - sh)) : 0ull);
                } else {
                    u64 w0 = ((u64)dmLDS[1] << 32) | (u64)dmLDS[0];
                    V = w0 << (-sb);
                }
                a = (cwv | __brevll(V)) & causal;
            }
            allowed[t] = a;
        }
        __syncthreads();

        // ---- S = Q K^T, both subtiles share each K fragment ----
        floatx4 sa[2][4];
#pragma unroll
        for (int s = 0; s < 2; ++s)
#pragma unroll
            for (int c = 0; c < 4; ++c) sa[s][c] = (floatx4){0.f, 0.f, 0.f, 0.f};
        __builtin_amdgcn_s_setprio(1);
#pragma unroll
        for (int c = 0; c < 4; ++c) {
            const unsigned short* kbase = Ks + (c * 16 + ln16) * 128;
#pragma unroll
            for (int ds = 0; ds < 4; ++ds) {
                short8 kf = *(const short8*)(kbase + (((ds * 4 + quad) ^ lsw) << 3));
                sa[0][c] = __builtin_amdgcn_mfma_f32_16x16x32_bf16(qf[0][ds], kf, sa[0][c], 0, 0, 0);
                sa[1][c] = __builtin_amdgcn_mfma_f32_16x16x32_bf16(qf[1][ds], kf, sa[1][c], 0, 0, 0);
            }
        }
        __builtin_amdgcn_s_setprio(0);

        // ---- mask + online softmax + P->LDS, per subtile ----
#pragma unroll
        for (int s = 0; s < 2; ++s) {
            u64 ash[4];
#pragma unroll
            for (int r = 0; r < 4; ++r)
                ash[r] = allowed[wave * 32 + s * 16 + quad * 4 + r] >> ln16;
            float sc[4][4];
#pragma unroll
            for (int c = 0; c < 4; ++c)
#pragma unroll
                for (int r = 0; r < 4; ++r) {
                    bool ok = (ash[r] >> (c * 16)) & 1ull;
                    sc[c][r] = ok ? sa[s][c][r] : -__builtin_inff();
                }
            float mloc[4];
#pragma unroll
            for (int r = 0; r < 4; ++r) {
                float mx = fmaxf(fmaxf(sc[0][r], sc[1][r]), fmaxf(sc[2][r], sc[3][r]));
#pragma unroll
                for (int d = 8; d >= 1; d >>= 1) mx = fmaxf(mx, __shfl_xor(mx, d, 64));
                mloc[r] = mx;
            }
            // exact defer-rescale: skip alpha path if no row's max grew
            // (skipped ops are exactly *1.0 -> bit-identical).
            bool nd = (mloc[0] > m_run[s][0]) | (mloc[1] > m_run[s][1]) |
                      (mloc[2] > m_run[s][2]) | (mloc[3] > m_run[s][3]);
            if (__any((int)nd)) {
#pragma unroll
                for (int r = 0; r < 4; ++r) {
                    float mn = fmaxf(m_run[s][r], mloc[r]);
                    float al = __expf(m_run[s][r] - mn);
                    m_run[s][r] = mn;
                    l_run[s][r] *= al;
#pragma unroll
                    for (int n = 0; n < 8; ++n) o4[s][n][r] *= al;
                }
            }
#pragma unroll
            for (int r = 0; r < 4; ++r) {
                float su = 0.f;
                float pvr[4];
#pragma unroll
                for (int c = 0; c < 4; ++c) {
                    float p = __expf(sc[c][r] - m_run[s][r]);
                    pvr[c] = p;
                    su += p;
                }
#pragma unroll
                for (int c = 0; c < 4; ++c)
                    psw[s][(quad * 4 + r) * PS_STRIDE + c * 16 + ln16] = f2bf(pvr[c]);
#pragma unroll
                for (int d = 8; d >= 1; d >>= 1) su += __shfl_xor(su, d, 64);
                l_run[s][r] += su;
            }
        }
        asm volatile("" ::: "memory");   // order psw writes before reads (per-wave DS in-order)

        short8 pf[2][2];
#pragma unroll
        for (int s = 0; s < 2; ++s) {
            pf[s][0] = *(const short8*)&psw[s][ln16 * PS_STRIDE + quad * 8];
            pf[s][1] = *(const short8*)&psw[s][ln16 * PS_STRIDE + 32 + quad * 8];
        }

        // ---- O += P V, both subtiles share each V fragment ----
        __builtin_amdgcn_s_setprio(1);
#pragma unroll
        for (int n = 0; n < 8; ++n) {
            const unsigned short* vbase = Vt + (n * 16 + ln16) * 64;
            short8 vf0 = *(const short8*)(vbase + ((quad ^ lsw) << 3));
            short8 vf1 = *(const short8*)(vbase + (((quad + 4) ^ lsw) << 3));
            o4[0][n] = __builtin_amdgcn_mfma_f32_16x16x32_bf16(pf[0][0], vf0, o4[0][n], 0, 0, 0);
            o4[0][n] = __builtin_amdgcn_mfma_f32_16x16x32_bf16(pf[0][1], vf1, o4[0][n], 0, 0, 0);
            o4[1][n] = __builtin_amdgcn_mfma_f32_16x16x32_bf16(pf[1][0], vf0, o4[1][n], 0, 0, 0);
            o4[1][n] = __builtin_amdgcn_mfma_f32_16x16x32_bf16(pf[1][1], vf1, o4[1][n], 0, 0, 0);
        }
        __builtin_amdgcn_s_setprio(0);
    }

    // ---- write partial (O bf16, m, l) ----
    int pidx = h * NJOBS + job;
    unsigned short* pOp = pO + (size_t)pidx * (128 * DHEAD);
#pragma unroll
    for (int s = 0; s < 2; ++s)
#pragma unroll
        for (int r = 0; r < 4; ++r) {
            int row = wave * 32 + s * 16 + quad * 4 + r;
            if (ln16 == 0) {
                pm[pidx * 128 + row] = m_run[s][r];
                pl[pidx * 128 + row] = l_run[s][r];
            }
#pragma unroll
            for (int n = 0; n < 8; ++n)
                pOp[row * DHEAD + n * 16 + ln16] = f2bf(o4[s][n][r]);
        }
}

// ---------------------------------------------------------------------------
// Merge partials -> normalized output. 256 blocks (h,Q) x 256 threads.
// ---------------------------------------------------------------------------
__global__ __launch_bounds__(256) void merge_out(const unsigned short* __restrict__ pO,
                                                 const float* __restrict__ pm,
                                                 const float* __restrict__ pl,
                                                 float* __restrict__ out) {
    int b = blockIdx.x;
    int h = b >> 5, Q = b & 31;
    int t = threadIdx.x;
    int row = t >> 1, half = t & 1;
    int p0 = h * NJOBS + pBase[Q];
    int cnt = pCnt[Q];

    float mp[6], lp[6];
    float ms = NEGBIG;
    for (int p = 0; p < cnt; ++p) {
        mp[p] = pm[(p0 + p) * 128 + row];
        lp[p] = pl[(p0 + p) * 128 + row];
        ms = fmaxf(ms, mp[p]);
    }
    float denom = 0.f, w[6];
    for (int p = 0; p < cnt; ++p) {
        w[p] = __expf(mp[p] - ms);
        denom += w[p] * lp[p];
    }
    float invl = 1.0f / denom;

    float acc[64];
#pragma unroll
    for (int i = 0; i < 64; ++i) acc[i] = 0.f;
    for (int p = 0; p < cnt; ++p) {
        const unsigned short* Op = pO + (size_t)(p0 + p) * (128 * DHEAD) + row * DHEAD + half * 64;
        float wp = w[p];
#pragma unroll
        for (int g = 0; g < 8; ++g) {
            ushort4 u0 = ((const ushort4*)Op)[g * 2];
            ushort4 u1 = ((const ushort4*)Op)[g * 2 + 1];
            acc[g * 8 + 0] += wp * bf2f(u0.x); acc[g * 8 + 1] += wp * bf2f(u0.y);
            acc[g * 8 + 2] += wp * bf2f(u0.z); acc[g * 8 + 3] += wp * bf2f(u0.w);
            acc[g * 8 + 4] += wp * bf2f(u1.x); acc[g * 8 + 5] += wp * bf2f(u1.y);
            acc[g * 8 + 6] += wp * bf2f(u1.z); acc[g * 8 + 7] += wp * bf2f(u1.w);
        }
    }
    float* op = out + ((size_t)h * S_LEN + Q * 128 + row) * DHEAD + half * 64;
#pragma unroll
    for (int g = 0; g < 16; ++g) {
        float4 c;
        c.x = acc[g * 4 + 0] * invl; c.y = acc[g * 4 + 1] * invl;
        c.z = acc[g * 4 + 2] * invl; c.w = acc[g * 4 + 3] * invl;
        ((float4*)op)[g] = c;
    }
}

// ---------------------------------------------------------------------------
extern "C" void kernel_launch(void* const* d_in, const int* in_sizes, int n_in,
                              void* d_out, int out_size, void* d_ws, size_t ws_size,
                              hipStream_t stream) {
    const float* q = (const float*)d_in[0];
    const float* k = (const float*)d_in[1];
    const float* v = (const float*)d_in[2];
    float* out = (float*)d_out;

    unsigned* col_m  = (unsigned*)d_ws;                          // 1024 u32
    unsigned* diag_m = col_m + 1024;                             // 1024 u32
    float* m_all   = (float*)(diag_m + 1024);                    // 512 f32
    float* inv_all = m_all + 512;                                // 512 f32
    unsigned short* kbf  = (unsigned short*)(inv_all + 512);     // 4M bf16 (8 MB)
    unsigned short* vtbf = kbf + (size_t)NHEAD * S_LEN * DHEAD;  // 4M bf16 (8 MB)
    float* scores = (float*)(vtbf + (size_t)NHEAD * S_LEN * DHEAD);          // 8 MB
    unsigned short* pO = (unsigned short*)(scores + (size_t)NHEAD * LASTQ * S_LEN); // 29.1 MB
    float* pm = (float*)(pO + (size_t)8 * NJOBS * 128 * DHEAD);  // 888*128 f32
    float* pl = pm + 8 * NJOBS * 128;

    prep_score<<<2048, 256, 0, stream>>>(q, k, v, kbf, vtbf, scores);
    row_stats<<<NHEAD * LASTQ / 4, 256, 0, stream>>>(scores, m_all, inv_all);
    pattern_finish<<<NHEAD * 2, 1024, 0, stream>>>(scores, m_all, inv_all, col_m, diag_m);
    sparse_attn_mfma<<<NHEAD * NJOBS, 256, 0, stream>>>(q, kbf, vtbf, col_m, diag_m, pO, pm, pl);
    merge_out<<<NHEAD * 32, 256, 0, stream>>>(pO, pm, pl, out);
}